// Round 1
// baseline (712.301 us; speedup 1.0000x reference)
//
#include <hip/hip_runtime.h>
#include <math.h>

#define DEV __device__ __forceinline__

DEV float gelu_exact(float v) {
    return 0.5f * v * (1.0f + erff(v * 0.7071067811865476f));
}

// ---------------------------------------------------------------------------
// K1: tiny MLPs -> conv weights sw[96][125] and mix matrix Mt[fv=96][gw=96]
// ---------------------------------------------------------------------------
__global__ __launch_bounds__(256) void wk(
    const float* __restrict__ spatial, const float* __restrict__ spherical,
    const float* __restrict__ bw1, const float* __restrict__ bb1,
    const float* __restrict__ bw2, const float* __restrict__ bb2,
    const float* __restrict__ bw3,
    const float* __restrict__ fw1, const float* __restrict__ fb1,
    const float* __restrict__ fw2, const float* __restrict__ fb2,
    const float* __restrict__ fw3,
    float* __restrict__ sw, float* __restrict__ Mt) {
    const int i = blockIdx.x * 256 + threadIdx.x;
    if (i < 1500) {
        const float a = spatial[2 * i], b = spatial[2 * i + 1];
        float ft[14];
        ft[0] = a; ft[1] = b;
        ft[2] = a * a; ft[3] = a * b; ft[4] = b * a; ft[5] = b * b;
#pragma unroll
        for (int k = 0; k < 4; ++k) {
            ft[6 + 2 * k] = ft[2 + k] * a;
            ft[7 + 2 * k] = ft[2 + k] * b;
        }
        float h1[8], h2[8];
#pragma unroll
        for (int j = 0; j < 8; ++j) {
            float s = bb1[j];
#pragma unroll
            for (int k = 0; k < 14; ++k) s = fmaf(bw1[j * 14 + k], ft[k], s);
            h1[j] = gelu_exact(s);
        }
#pragma unroll
        for (int j = 0; j < 8; ++j) {
            float s = bb2[j];
#pragma unroll
            for (int k = 0; k < 8; ++k) s = fmaf(bw2[j * 8 + k], h1[k], s);
            h2[j] = gelu_exact(s);
        }
        const int o = i / 12, v = i % 12;
#pragma unroll
        for (int c = 0; c < 8; ++c) {
            float s = 0.f;
#pragma unroll
            for (int k = 0; k < 8; ++k) s = fmaf(bw3[c * 8 + k], h2[k], s);
            sw[(c * 12 + v) * 125 + o] = s;   // channel ch = cin*12+v, tap o = A*25+B*5+C
        }
    } else if (i < 1644) {
        const int r = i - 1500;
        const float s0 = spherical[r];
        float ft[3];
        ft[0] = s0; ft[1] = s0 * s0; ft[2] = s0 * s0 * s0;
        float h1[8], h2[8];
#pragma unroll
        for (int j = 0; j < 8; ++j) {
            float s = fb1[j];
#pragma unroll
            for (int k = 0; k < 3; ++k) s = fmaf(fw1[j * 3 + k], ft[k], s);
            h1[j] = gelu_exact(s);
        }
#pragma unroll
        for (int j = 0; j < 8; ++j) {
            float s = fb2[j];
#pragma unroll
            for (int k = 0; k < 8; ++k) s = fmaf(fw2[j * 8 + k], h1[k], s);
            h2[j] = gelu_exact(s);
        }
        const int v = r / 12, w = r % 12;     // spherical row = (v, w)
#pragma unroll
        for (int c = 0; c < 64; ++c) {        // c = f*8 + g
            float s = 0.f;
#pragma unroll
            for (int k = 0; k < 8; ++k) s = fmaf(fw3[c * 8 + k], h2[k], s);
            const int f = c >> 3, g = c & 7;
            // Mt[fv][gw] = fw[g,f,v,w];  fv = f*12+v, gw = g*12+w
            Mt[(f * 12 + v) * 96 + g * 12 + w] = s;
        }
    }
}

// ---------------------------------------------------------------------------
// K2: depthwise 5x5x5 conv, SAME/zero pad.  One block = 1 (b,ch), tile 64x8x8.
// Thread tile: 4x * 2y * 2z.  Writes y into d_out (reused as staging).
// ---------------------------------------------------------------------------
__global__ __launch_bounds__(256) void ck(const float* __restrict__ x,
                                          const float* __restrict__ sw,
                                          float* __restrict__ y) {
    const int ch = blockIdx.y, b = blockIdx.z;
    const int ty = (blockIdx.x & 7) << 3;
    const int tz = (blockIdx.x >> 3) << 3;
    const int t = threadIdx.x;
    const int xq = t & 15, x0 = xq << 2;
    const int y0 = ty + (((t >> 4) & 3) << 1);
    const int z0 = tz + ((t >> 6) << 1);       // wave-uniform
    const long cb = (long)(b * 96 + ch) << 18; // *262144
    const float* __restrict__ xb = x + cb;
    float* __restrict__ yb = y + cb;
    const float* __restrict__ w = sw + ch * 125;  // uniform -> scalar loads

    float acc[2][2][4];
#pragma unroll
    for (int i = 0; i < 2; ++i)
#pragma unroll
        for (int j = 0; j < 2; ++j)
#pragma unroll
            for (int k = 0; k < 4; ++k) acc[i][j][k] = 0.f;

#pragma unroll
    for (int hz = 0; hz < 6; ++hz) {
        const int zz = z0 + hz - 2;
        if (zz < 0 || zz >= 64) continue;      // wave-uniform branch
#pragma unroll
        for (int hy = 0; hy < 6; ++hy) {
            const int yy = y0 + hy - 2;
            if (yy >= 0 && yy < 64) {
                const float* row = xb + (zz << 12) + (yy << 6);
                const float4 v4 = *(const float4*)(row + x0);
                float f[8];
                f[0] = (xq > 0) ? row[x0 - 2] : 0.f;
                f[1] = (xq > 0) ? row[x0 - 1] : 0.f;
                f[2] = v4.x; f[3] = v4.y; f[4] = v4.z; f[5] = v4.w;
                f[6] = (xq < 15) ? row[x0 + 4] : 0.f;
                f[7] = (xq < 15) ? row[x0 + 5] : 0.f;
#pragma unroll
                for (int dz = 0; dz < 2; ++dz) {
                    const int A = hz - dz;
                    if (A < 0 || A > 4) continue;   // folded at compile time
#pragma unroll
                    for (int dy = 0; dy < 2; ++dy) {
                        const int B = hy - dy;
                        if (B < 0 || B > 4) continue;
                        const float* wr = w + (A * 5 + B) * 5;
#pragma unroll
                        for (int C = 0; C < 5; ++C) {
                            const float wv = wr[C];
#pragma unroll
                            for (int dx = 0; dx < 4; ++dx)
                                acc[dz][dy][dx] = fmaf(f[C + dx], wv, acc[dz][dy][dx]);
                        }
                    }
                }
            }
        }
    }
#pragma unroll
    for (int dz = 0; dz < 2; ++dz)
#pragma unroll
        for (int dy = 0; dy < 2; ++dy) {
            float4 o;
            o.x = acc[dz][dy][0]; o.y = acc[dz][dy][1];
            o.z = acc[dz][dy][2]; o.w = acc[dz][dy][3];
            *(float4*)(yb + ((z0 + dz) << 12) + ((y0 + dy) << 6) + x0) = o;
        }
}

// ---------------------------------------------------------------------------
// K3: in-place per-point 96->96 mix + bias.  Block stages its 128-point slice
// (all 96 fv) into LDS, syncs, then overwrites the same slice.
// Wave w handles 24 gw; lane holds 2 points.
// ---------------------------------------------------------------------------
__global__ __launch_bounds__(256) void ek(float* __restrict__ io,
                                          const float* __restrict__ Mt,
                                          const float* __restrict__ bias) {
    __shared__ float yl[96][128];
    const int t = threadIdx.x;
    float* base = io + (((long)blockIdx.y * 96) << 18) + ((long)blockIdx.x << 7);
#pragma unroll
    for (int it = 0; it < 12; ++it) {
        const int i = it * 256 + t;          // [0, 3072): fv = i>>5, chunk = i&31
        const int fv = i >> 5, c4 = (i & 31) << 2;
        const float4 v = *(const float4*)(base + (long)fv * 262144 + c4);
        *(float4*)&yl[fv][c4] = v;
    }
    __syncthreads();
    const int lane = t & 63;
    const int g0 = __builtin_amdgcn_readfirstlane(t >> 6) * 24;  // force SGPR
    float acc0[24], acc1[24];
#pragma unroll
    for (int j = 0; j < 24; ++j) { acc0[j] = 0.f; acc1[j] = 0.f; }
    for (int fv = 0; fv < 96; ++fv) {
        const float2 yv = *(const float2*)&yl[fv][lane << 1];
        const float* __restrict__ mrow = Mt + fv * 96 + g0;  // uniform -> s_load
#pragma unroll
        for (int j = 0; j < 24; ++j) {
            const float m = mrow[j];
            acc0[j] = fmaf(yv.x, m, acc0[j]);
            acc1[j] = fmaf(yv.y, m, acc1[j]);
        }
    }
#pragma unroll
    for (int j = 0; j < 24; ++j) {
        const int gw = g0 + j;
        const float bg = bias[gw / 12];
        float2 o;
        o.x = acc0[j] + bg;
        o.y = acc1[j] + bg;
        *(float2*)(base + (long)gw * 262144 + (lane << 1)) = o;
    }
}

// ---------------------------------------------------------------------------
extern "C" void kernel_launch(void* const* d_in, const int* in_sizes, int n_in,
                              void* d_out, int out_size, void* d_ws, size_t ws_size,
                              hipStream_t stream) {
    const float* x        = (const float*)d_in[0];
    const float* spatial  = (const float*)d_in[1];
    const float* spherical= (const float*)d_in[2];
    const float* bw1 = (const float*)d_in[3];
    const float* bb1 = (const float*)d_in[4];
    const float* bw2 = (const float*)d_in[5];
    const float* bb2 = (const float*)d_in[6];
    const float* bw3 = (const float*)d_in[7];
    const float* fw1 = (const float*)d_in[8];
    const float* fb1 = (const float*)d_in[9];
    const float* fw2 = (const float*)d_in[10];
    const float* fb2 = (const float*)d_in[11];
    const float* fw3 = (const float*)d_in[12];
    const float* bias = (const float*)d_in[13];

    float* sw = (float*)d_ws;           // 12000 floats
    float* Mt = (float*)d_ws + 12032;   // 9216 floats
    float* out = (float*)d_out;         // also conv staging buffer

    hipLaunchKernelGGL(wk, dim3(7), dim3(256), 0, stream,
                       spatial, spherical, bw1, bb1, bw2, bb2, bw3,
                       fw1, fb1, fw2, fb2, fw3, sw, Mt);
    hipLaunchKernelGGL(ck, dim3(64, 96, 2), dim3(256), 0, stream, x, sw, out);
    hipLaunchKernelGGL(ek, dim3(2048, 2, 1), dim3(256), 0, stream, out, Mt, bias);
    (void)in_sizes; (void)n_in; (void)out_size; (void)ws_size;
}

// Round 2
// 621.543 us; speedup vs baseline: 1.1460x; 1.1460x over previous
//
#include <hip/hip_runtime.h>
#include <math.h>

#define DEV __device__ __forceinline__

DEV float gelu_exact(float v) {
    return 0.5f * v * (1.0f + erff(v * 0.7071067811865476f));
}

typedef __attribute__((ext_vector_type(8))) short bf16x8;
typedef __attribute__((ext_vector_type(4))) float f32x4;

DEV short f2b(float f) {
    unsigned u = __builtin_bit_cast(unsigned, f);
    unsigned r = (u + 0x7fffu + ((u >> 16) & 1u)) >> 16;
    return (short)r;
}

// ---------------------------------------------------------------------------
// K1: tiny MLPs -> conv weights sw[96][125] and mix matrix Mt[fv=96][gw=96]
// ---------------------------------------------------------------------------
__global__ __launch_bounds__(256) void wk(
    const float* __restrict__ spatial, const float* __restrict__ spherical,
    const float* __restrict__ bw1, const float* __restrict__ bb1,
    const float* __restrict__ bw2, const float* __restrict__ bb2,
    const float* __restrict__ bw3,
    const float* __restrict__ fw1, const float* __restrict__ fb1,
    const float* __restrict__ fw2, const float* __restrict__ fb2,
    const float* __restrict__ fw3,
    float* __restrict__ sw, float* __restrict__ Mt) {
    const int i = blockIdx.x * 256 + threadIdx.x;
    if (i < 1500) {
        const float a = spatial[2 * i], b = spatial[2 * i + 1];
        float ft[14];
        ft[0] = a; ft[1] = b;
        ft[2] = a * a; ft[3] = a * b; ft[4] = b * a; ft[5] = b * b;
#pragma unroll
        for (int k = 0; k < 4; ++k) {
            ft[6 + 2 * k] = ft[2 + k] * a;
            ft[7 + 2 * k] = ft[2 + k] * b;
        }
        float h1[8], h2[8];
#pragma unroll
        for (int j = 0; j < 8; ++j) {
            float s = bb1[j];
#pragma unroll
            for (int k = 0; k < 14; ++k) s = fmaf(bw1[j * 14 + k], ft[k], s);
            h1[j] = gelu_exact(s);
        }
#pragma unroll
        for (int j = 0; j < 8; ++j) {
            float s = bb2[j];
#pragma unroll
            for (int k = 0; k < 8; ++k) s = fmaf(bw2[j * 8 + k], h1[k], s);
            h2[j] = gelu_exact(s);
        }
        const int o = i / 12, v = i % 12;
#pragma unroll
        for (int c = 0; c < 8; ++c) {
            float s = 0.f;
#pragma unroll
            for (int k = 0; k < 8; ++k) s = fmaf(bw3[c * 8 + k], h2[k], s);
            sw[(c * 12 + v) * 125 + o] = s;   // channel ch = cin*12+v, tap o = A*25+B*5+C
        }
    } else if (i < 1644) {
        const int r = i - 1500;
        const float s0 = spherical[r];
        float ft[3];
        ft[0] = s0; ft[1] = s0 * s0; ft[2] = s0 * s0 * s0;
        float h1[8], h2[8];
#pragma unroll
        for (int j = 0; j < 8; ++j) {
            float s = fb1[j];
#pragma unroll
            for (int k = 0; k < 3; ++k) s = fmaf(fw1[j * 3 + k], ft[k], s);
            h1[j] = gelu_exact(s);
        }
#pragma unroll
        for (int j = 0; j < 8; ++j) {
            float s = fb2[j];
#pragma unroll
            for (int k = 0; k < 8; ++k) s = fmaf(fw2[j * 8 + k], h1[k], s);
            h2[j] = gelu_exact(s);
        }
        const int v = r / 12, w = r % 12;     // spherical row = (v, w)
#pragma unroll
        for (int c = 0; c < 64; ++c) {        // c = f*8 + g
            float s = 0.f;
#pragma unroll
            for (int k = 0; k < 8; ++k) s = fmaf(fw3[c * 8 + k], h2[k], s);
            const int f = c >> 3, g = c & 7;
            // Mt[fv][gw] = fw[g,f,v,w];  fv = f*12+v, gw = g*12+w
            Mt[(f * 12 + v) * 96 + g * 12 + w] = s;
        }
    }
}

// ---------------------------------------------------------------------------
// K2: depthwise 5x5x5 conv, SAME/zero pad.  One block = 1 (b,ch), tile 64x8x8.
// Thread tile: 4x * 2y * 2z.  Halo in x comes from neighbor lanes via shfl
// (lanes 0..15 of each 16-group cover the full x-line) -> 1 VMEM load/row.
// ---------------------------------------------------------------------------
__global__ __launch_bounds__(256) void ck(const float* __restrict__ x,
                                          const float* __restrict__ sw,
                                          float* __restrict__ y) {
    const int ch = blockIdx.y, b = blockIdx.z;
    const int ty = (blockIdx.x & 7) << 3;
    const int tz = (blockIdx.x >> 3) << 3;
    const int t = threadIdx.x;
    const int xq = t & 15, x0 = xq << 2;
    const int y0 = ty + (((t >> 4) & 3) << 1);
    const int z0 = tz + ((t >> 6) << 1);       // wave-uniform
    const long cb = (long)(b * 96 + ch) << 18; // *262144
    const float* __restrict__ xb = x + cb;
    float* __restrict__ yb = y + cb;
    const float* __restrict__ w = sw + ch * 125;  // uniform -> scalar loads

    float acc[2][2][4];
#pragma unroll
    for (int i = 0; i < 2; ++i)
#pragma unroll
        for (int j = 0; j < 2; ++j)
#pragma unroll
            for (int k = 0; k < 4; ++k) acc[i][j][k] = 0.f;

#pragma unroll
    for (int hz = 0; hz < 6; ++hz) {
        const int zz = z0 + hz - 2;
        if (zz < 0 || zz >= 64) continue;      // wave-uniform branch
#pragma unroll
        for (int hy = 0; hy < 6; ++hy) {
            const int yy = y0 + hy - 2;
            // yy is uniform within each 16-lane shuffle group (lanes 0..15
            // share y0,z0), so the divergent branch never splits a group.
            if (yy >= 0 && yy < 64) {
                const float* row = xb + (zz << 12) + (yy << 6);
                const float4 v4 = *(const float4*)(row + x0);
                const float uz = __shfl_up(v4.z, 1, 16);
                const float uw = __shfl_up(v4.w, 1, 16);
                const float dx_ = __shfl_down(v4.x, 1, 16);
                const float dy_ = __shfl_down(v4.y, 1, 16);
                float f[8];
                f[0] = (xq > 0) ? uz : 0.f;
                f[1] = (xq > 0) ? uw : 0.f;
                f[2] = v4.x; f[3] = v4.y; f[4] = v4.z; f[5] = v4.w;
                f[6] = (xq < 15) ? dx_ : 0.f;
                f[7] = (xq < 15) ? dy_ : 0.f;
#pragma unroll
                for (int dz = 0; dz < 2; ++dz) {
                    const int A = hz - dz;
                    if (A < 0 || A > 4) continue;   // folded at compile time
#pragma unroll
                    for (int dy = 0; dy < 2; ++dy) {
                        const int B = hy - dy;
                        if (B < 0 || B > 4) continue;
                        const float* wr = w + (A * 5 + B) * 5;
#pragma unroll
                        for (int C = 0; C < 5; ++C) {
                            const float wv = wr[C];
#pragma unroll
                            for (int dx = 0; dx < 4; ++dx)
                                acc[dz][dy][dx] = fmaf(f[C + dx], wv, acc[dz][dy][dx]);
                        }
                    }
                }
            }
        }
    }
#pragma unroll
    for (int dz = 0; dz < 2; ++dz)
#pragma unroll
        for (int dy = 0; dy < 2; ++dy) {
            float4 o;
            o.x = acc[dz][dy][0]; o.y = acc[dz][dy][1];
            o.z = acc[dz][dy][2]; o.w = acc[dz][dy][3];
            *(float4*)(yb + ((z0 + dz) << 12) + ((y0 + dy) << 6) + x0) = o;
        }
}

// ---------------------------------------------------------------------------
// K3: in-place per-point 96->96 mix + bias as bf16 MFMA GEMM.
// Block = 128 pts x 96 gw.  Wave w owns pts [pt0+32w, +32): 2 n-tiles.
// A = M^T (m=gw, k=fv), B = y (k=fv, n=pt).  D: row(m)=quad*4+r, col(n)=lane&15.
// All reads land in registers before any store -> in-place safe (pts disjoint
// across waves/blocks).
// ---------------------------------------------------------------------------
__global__ __launch_bounds__(256) void ek(float* __restrict__ io,
                                          const float* __restrict__ Mt,
                                          const float* __restrict__ bias) {
    const int t = threadIdx.x;
    const int lane = t & 63;
    const int wv = t >> 6;                     // wave id 0..3
    const int l15 = lane & 15, quad = lane >> 4;
    const long b_off = ((long)blockIdx.y * 96) << 18;
    const int pt0 = (blockIdx.x << 7) + (wv << 5);   // this wave's 32 pts

    // A-frags: M^T  (6 m-tiles x 3 ksteps), A[m=lane&15 -> gw][k=quad*8+j -> fv]
    bf16x8 Af[6][3];
#pragma unroll
    for (int mt = 0; mt < 6; ++mt)
#pragma unroll
        for (int ks = 0; ks < 3; ++ks)
#pragma unroll
            for (int j = 0; j < 8; ++j) {
                const int fv = ks * 32 + quad * 8 + j;
                Af[mt][ks][j] = f2b(Mt[fv * 96 + mt * 16 + l15]);
            }

    // B-frags: y  (2 n-tiles x 3 ksteps), B[k=quad*8+j -> fv][n=lane&15 -> pt]
    bf16x8 Bf[2][3];
#pragma unroll
    for (int nt = 0; nt < 2; ++nt)
#pragma unroll
        for (int ks = 0; ks < 3; ++ks)
#pragma unroll
            for (int j = 0; j < 8; ++j) {
                const int fv = ks * 32 + quad * 8 + j;
                Bf[nt][ks][j] = f2b(io[b_off + ((long)fv << 18) + pt0 + nt * 16 + l15]);
            }

#pragma unroll
    for (int mt = 0; mt < 6; ++mt)
#pragma unroll
        for (int nt = 0; nt < 2; ++nt) {
            f32x4 c = {0.f, 0.f, 0.f, 0.f};
#pragma unroll
            for (int ks = 0; ks < 3; ++ks)
                c = __builtin_amdgcn_mfma_f32_16x16x32_bf16(Af[mt][ks], Bf[nt][ks], c, 0, 0, 0);
#pragma unroll
            for (int r = 0; r < 4; ++r) {
                const int gw = mt * 16 + quad * 4 + r;
                io[b_off + ((long)gw << 18) + pt0 + nt * 16 + l15] = c[r] + bias[gw / 12];
            }
        }
}

// ---------------------------------------------------------------------------
extern "C" void kernel_launch(void* const* d_in, const int* in_sizes, int n_in,
                              void* d_out, int out_size, void* d_ws, size_t ws_size,
                              hipStream_t stream) {
    const float* x        = (const float*)d_in[0];
    const float* spatial  = (const float*)d_in[1];
    const float* spherical= (const float*)d_in[2];
    const float* bw1 = (const float*)d_in[3];
    const float* bb1 = (const float*)d_in[4];
    const float* bw2 = (const float*)d_in[5];
    const float* bb2 = (const float*)d_in[6];
    const float* bw3 = (const float*)d_in[7];
    const float* fw1 = (const float*)d_in[8];
    const float* fb1 = (const float*)d_in[9];
    const float* fw2 = (const float*)d_in[10];
    const float* fb2 = (const float*)d_in[11];
    const float* fw3 = (const float*)d_in[12];
    const float* bias = (const float*)d_in[13];

    float* sw = (float*)d_ws;           // 12000 floats
    float* Mt = (float*)d_ws + 12032;   // 9216 floats
    float* out = (float*)d_out;         // also conv staging buffer

    hipLaunchKernelGGL(wk, dim3(7), dim3(256), 0, stream,
                       spatial, spherical, bw1, bb1, bw2, bb2, bw3,
                       fw1, fb1, fw2, fb2, fw3, sw, Mt);
    hipLaunchKernelGGL(ck, dim3(64, 96, 2), dim3(256), 0, stream, x, sw, out);
    hipLaunchKernelGGL(ek, dim3(2048, 2, 1), dim3(256), 0, stream, out, Mt, bias);
    (void)in_sizes; (void)n_in; (void)out_size; (void)ws_size;
}